// Round 12
// baseline (303.316 us; speedup 1.0000x reference)
//
#include <hip/hip_runtime.h>
#include <stdint.h>

// ---------------------------------------------------------------------------
// EmbraceNet fused: out[b,e] = relu(x_f @ W_f + b_f)[b,e],  f = idx[b,e]
// idx = categorical(key=42): partitionable threefry, bits = y0^y1 of
// threefry2x32((0,42), (0, (e*4096+b)*4+f)); argmax over bits>>9, strict >.
// PASS since R4 (absmax 0.031).
//
// R22 == R20/R21 resubmitted (both benches were infra failures: "container
// failed twice", no kernel verdict; source passed 3 audits; R2->R3
// precedent shows this error resolving on unmodified resubmission).
// R20: occupancy lever, never yet executed. R17's gemm with 512 threads:
// 8 waves of 64x32 (2Mx4N) on the same 128x128 tile, BK=64, same 64 KiB
// double-buffered LDS, same XOR swizzle, same barrier count (68), same
// staging addresses (each wave stages 2 chunks of A and B instead of 4).
// Waves/CU 8 -> 16 (2 -> 4 waves/SIMD); per-wave state halves
// (acc[4][2]+res[4][2]) so 4 waves/SIMD fits the unified VGPR/AGPR file;
// (512,2) bound == empirical 128-VGPR cap (R11/R14/R16: exactly 128, no
// spill at this state size). Single variable vs R17: wave granularity.
// Pre-commit: infra failure or gemm >= 87us -> revert to R17, close.
// ---------------------------------------------------------------------------

typedef short short8 __attribute__((ext_vector_type(8)));
typedef float floatx4 __attribute__((ext_vector_type(4)));

#define B_DIM 4096
#define K_DIM 1024
#define E_DIM 2048

__device__ __forceinline__ uint32_t rotl32(uint32_t x, uint32_t r) {
  return __builtin_amdgcn_alignbit(x, x, 32u - r);
}

__device__ __forceinline__ uint16_t f2bf(float x) {
  uint32_t u = __float_as_uint(x);
  u += 0x7FFFu + ((u >> 16) & 1u);
  return (uint16_t)(u >> 16);
}

// JAX threefry2x32, key = (0, 42)
__device__ __forceinline__ void threefry(uint32_t x0, uint32_t x1,
                                         uint32_t& o0, uint32_t& o1) {
  const uint32_t ks0 = 0u;
  const uint32_t ks1 = 42u;
  const uint32_t ks2 = 0x1BD11BDAu ^ 42u;
  x0 += ks0; x1 += ks1;
#define TF_R(r) { x0 += x1; x1 = rotl32(x1, r); x1 ^= x0; }
  TF_R(13) TF_R(15) TF_R(26) TF_R(6)
  x0 += ks1; x1 += ks2 + 1u;
  TF_R(17) TF_R(29) TF_R(16) TF_R(24)
  x0 += ks2; x1 += ks0 + 2u;
  TF_R(13) TF_R(15) TF_R(26) TF_R(6)
  x0 += ks0; x1 += ks1 + 3u;
  TF_R(17) TF_R(29) TF_R(16) TF_R(24)
  x0 += ks1; x1 += ks2 + 4u;
  TF_R(13) TF_R(15) TF_R(26) TF_R(6)
  x0 += ks2; x1 += ks0 + 5u;
#undef TF_R
  o0 = x0; o1 = x1;
}

// 8192 blocks x 256 threads. Unchanged since R10 (verified).
__global__ __launch_bounds__(256) void prep_kernel(
    const float* __restrict__ x0, const float* __restrict__ x1,
    const float* __restrict__ x2, const float* __restrict__ x3,
    const float* __restrict__ W0, const float* __restrict__ W1,
    const float* __restrict__ W2, const float* __restrict__ W3,
    uint16_t* __restrict__ xb, uint16_t* __restrict__ Wt,
    uint8_t* __restrict__ idx1) {
  __shared__ float tile[32][33];
  const uint32_t g = blockIdx.x;       // 0..8191
  const int t = threadIdx.x;
  const int f = g >> 11;               // plane 0..3
  const uint32_t ip = g & 2047u;       // tile/chunk within plane

  // ---- issue x loads: plane f, 8 consecutive floats per thread ----
  const float* x = (f == 0) ? x0 : (f == 1) ? x1 : (f == 2) ? x2 : x3;
  const size_t xoff = ((size_t)ip * 256 + t) * 8;
  float4 v0 = *(const float4*)(x + xoff);
  float4 v1 = *(const float4*)(x + xoff + 4);

  // ---- issue W loads: 32x32 tile ip of plane f ----
  const float* W = (f == 0) ? W0 : (f == 1) ? W1 : (f == 2) ? W2 : W3;
  const int e0 = (int)(ip & 63) * 32, k0 = (int)(ip >> 6) * 32;
  const int tx = t & 31, ty = t >> 5;
  float wv[4];
#pragma unroll
  for (int i = 0; i < 4; ++i)
    wv[i] = W[(size_t)(k0 + ty + i * 8) * E_DIM + e0 + tx];

  // ---- threefry crunch: outputs o0..o0+3, pack 2 bits each ----
  const uint32_t o0i = (g * 256u + t) * 4u;
  uint32_t byte = 0;
#pragma unroll
  for (uint32_t q = 0; q < 4; ++q) {
    uint32_t c = (o0i + q) << 2;
    uint32_t best = 0, bi = 0;
#pragma unroll
    for (uint32_t ff = 0; ff < 4; ++ff) {
      uint32_t y0, y1;
      threefry(0u, c + ff, y0, y1);
      uint32_t m = (y0 ^ y1) >> 9;
      if (ff == 0) best = m;
      else if (m > best) { best = m; bi = ff; }
    }
    byte |= bi << (2 * q);
  }
  idx1[g * 256u + t] = (uint8_t)byte;

  // ---- x store: 8 bf16 = 16B ----
  {
    union { uint16_t h[8]; uint64_t q[2]; } p;
    p.h[0] = f2bf(v0.x); p.h[1] = f2bf(v0.y);
    p.h[2] = f2bf(v0.z); p.h[3] = f2bf(v0.w);
    p.h[4] = f2bf(v1.x); p.h[5] = f2bf(v1.y);
    p.h[6] = f2bf(v1.z); p.h[7] = f2bf(v1.w);
    uint64_t* dst = (uint64_t*)(xb + (size_t)f * B_DIM * K_DIM + xoff);
    dst[0] = p.q[0]; dst[1] = p.q[1];
  }

  // ---- W transpose via LDS ----
#pragma unroll
  for (int i = 0; i < 4; ++i) tile[ty + i * 8][tx] = wv[i];
  __syncthreads();
  {
    const int el = t >> 3, kc = (t & 7) * 4;
    union { uint16_t h[4]; uint64_t q; } p;
#pragma unroll
    for (int i = 0; i < 4; ++i) p.h[i] = f2bf(tile[kc + i][el]);
    uint16_t* dst = Wt + (size_t)f * E_DIM * K_DIM;
    *(uint64_t*)(dst + (size_t)(e0 + el) * K_DIM + k0 + kc) = p.q;
  }
}

__device__ __forceinline__ void async16(const uint16_t* g, uint16_t* lds) {
  __builtin_amdgcn_global_load_lds(
      (const __attribute__((address_space(1))) void*)g,
      (__attribute__((address_space(3))) void*)lds, 16, 0, 0);
}

// 512 threads (8 waves, 2M x 4N of 64x32), 128x128 tile, BK=64, f-loop
// inside, double-buffered LDS (64KB), one barrier per 64-K iter (64 total).
// LDS[row][pos] holds global k-chunk pos^(row&7) (XOR swizzle, 8x16B
// chunks) -- layout and staging addresses identical to R17; each wave
// stages 2 chunks of A and 2 of B (chunk = 8 rows x 64 k).
__global__ __launch_bounds__(512, 2) void gemm_fused(
    const uint16_t* __restrict__ Ab, const uint16_t* __restrict__ Bbt,
    const uint32_t* __restrict__ idx2,
    const float* __restrict__ bias0, const float* __restrict__ bias1,
    const float* __restrict__ bias2, const float* __restrict__ bias3,
    float* __restrict__ out) {
  __shared__ uint16_t As[2][128 * 64];
  __shared__ uint16_t Bs[2][128 * 64];

  const int tid = threadIdx.x;
  const int w = tid >> 6;        // 0..7
  const int l = tid & 63;

  // bijective XCD-chunked swizzle: 512 blocks = 8 XCDs x 64 contiguous
  const int flat = (int)(blockIdx.y * gridDim.x + blockIdx.x);
  const int swz = (flat & 7) * 64 + (flat >> 3);
  const int mBase = (swz >> 4) * 128;   // 32 m-tiles
  const int nBase = (swz & 15) * 128;   // 16 n-tiles

  const int wm = (w >> 2) * 64;         // 0,64
  const int wn = (w & 3) * 32;          // 0,32,64,96
  // staging: wave w stages chunks 2w, 2w+1 (chunk = 8 rows of 64k);
  // lane -> row sr, swizzled k-chunk (same map as R17)
  const int sr = l >> 3;                 // 0..7 row within chunk
  const int skc = ((l & 7) ^ sr) * 8;    // global k-elem offset (swizzled)
  const int fr = l & 15, fq = l >> 4;

  const int b_hi0 = (mBase + wm) >> 4;
  uint32_t iw[2][4];
#pragma unroll
  for (int ni = 0; ni < 2; ++ni) {
    int col = nBase + wn + ni * 16 + fr;
#pragma unroll
    for (int mi = 0; mi < 4; ++mi)
      iw[ni][mi] = idx2[(size_t)col * (B_DIM / 16) + b_hi0 + mi];
  }

  floatx4 res[4][2] = {};

#pragma unroll 1
  for (int f = 0; f < 4; ++f) {
    const uint16_t* A = Ab  + (size_t)f * B_DIM * K_DIM + (size_t)mBase * K_DIM;
    const uint16_t* B = Bbt + (size_t)f * E_DIM * K_DIM + (size_t)nBase * K_DIM;
    // wave w stages chunks 2w, 2w+1 of each matrix (rows 16w..16w+15)
    const uint16_t* Aw = A + (size_t)(16 * w + sr) * K_DIM + skc;
    const uint16_t* Bw = B + (size_t)(16 * w + sr) * K_DIM + skc;

    floatx4 acc[4][2] = {};

#pragma unroll
    for (int tt = 0; tt < 2; ++tt) {
      async16(Aw + (size_t)(8 * tt) * K_DIM, &As[0][(2 * w + tt) * 512]);
      async16(Bw + (size_t)(8 * tt) * K_DIM, &Bs[0][(2 * w + tt) * 512]);
    }
    __syncthreads();

    int buf = 0;
#pragma unroll 1
    for (int kt = 0; kt < 16; ++kt) {
      int kn = (kt + 1) * 64;
      if (kt + 1 < 16) {  // next 64-K tile into other buffer, before compute
#pragma unroll
        for (int tt = 0; tt < 2; ++tt) {
          async16(Aw + (size_t)(8 * tt) * K_DIM + kn, &As[buf ^ 1][(2 * w + tt) * 512]);
          async16(Bw + (size_t)(8 * tt) * K_DIM + kn, &Bs[buf ^ 1][(2 * w + tt) * 512]);
        }
      }
#pragma unroll
      for (int h = 0; h < 2; ++h) {
        short8 a[4], b[2];
        const int ch = h * 4 + fq;
#pragma unroll
        for (int mi = 0; mi < 4; ++mi) {
          int row = wm + mi * 16 + fr;
          a[mi] = *(const short8*)&As[buf][row * 64 + (ch ^ (fr & 7)) * 8];
        }
#pragma unroll
        for (int ni = 0; ni < 2; ++ni) {
          int row = wn + ni * 16 + fr;
          b[ni] = *(const short8*)&Bs[buf][row * 64 + (ch ^ (fr & 7)) * 8];
        }
#pragma unroll
        for (int mi = 0; mi < 4; ++mi)
#pragma unroll
          for (int ni = 0; ni < 2; ++ni)
            acc[mi][ni] = __builtin_amdgcn_mfma_f32_16x16x32_bf16(
                a[mi], b[ni], acc[mi][ni], 0, 0, 0);
      }
      __syncthreads();
      buf ^= 1;
    }

    const float* bias = (f == 0) ? bias0 : (f == 1) ? bias1
                      : (f == 2) ? bias2 : bias3;
#pragma unroll
    for (int ni = 0; ni < 2; ++ni) {
      float bvf = bias[nBase + wn + ni * 16 + fr];
#pragma unroll
      for (int mi = 0; mi < 4; ++mi) {
        uint32_t wd = iw[ni][mi];
#pragma unroll
        for (int r = 0; r < 4; ++r) {
          uint32_t sel = (wd >> (2 * (fq * 4 + r))) & 3u;
          if (sel == (uint32_t)f) res[mi][ni][r] = acc[mi][ni][r] + bvf;
        }
      }
    }
  }

  // dense coalesced store with relu. C/D: col=lane&15, row=(lane>>4)*4+reg
#pragma unroll
  for (int ni = 0; ni < 2; ++ni) {
    int col = nBase + wn + ni * 16 + fr;
#pragma unroll
    for (int mi = 0; mi < 4; ++mi) {
      int row0 = mBase + wm + mi * 16 + fq * 4;
#pragma unroll
      for (int r = 0; r < 4; ++r) {
        float o = res[mi][ni][r];
        __builtin_nontemporal_store(o > 0.f ? o : 0.f,
                                    &out[(size_t)(row0 + r) * E_DIM + col]);
      }
    }
  }
}

extern "C" void kernel_launch(void* const* d_in, const int* in_sizes, int n_in,
                              void* d_out, int out_size, void* d_ws, size_t ws_size,
                              hipStream_t stream) {
  const float* x[4]; const float* W[4]; const float* bs[4];
  for (int f = 0; f < 4; ++f) {
    x[f]  = (const float*)d_in[3 * f + 0];
    W[f]  = (const float*)d_in[3 * f + 1];
    bs[f] = (const float*)d_in[3 * f + 2];
  }
  char* ws = (char*)d_ws;
  uint16_t* xb  = (uint16_t*)ws;                               // 32 MB
  uint16_t* Wt  = (uint16_t*)(ws + (size_t)32 * 1024 * 1024);  // 16 MB
  uint8_t*  idx1 = (uint8_t*)(ws + (size_t)48 * 1024 * 1024);  //  2 MB
  float* out = (float*)d_out;

  prep_kernel<<<dim3(8192), dim3(256), 0, stream>>>(
      x[0], x[1], x[2], x[3], W[0], W[1], W[2], W[3], xb, Wt, idx1);
  gemm_fused<<<dim3(E_DIM / 128, B_DIM / 128), dim3(512), 0, stream>>>(
      xb, Wt, (const uint32_t*)idx1, bs[0], bs[1], bs[2], bs[3], out);
}

// Round 13
// 255.522 us; speedup vs baseline: 1.1870x; 1.1870x over previous
//
#include <hip/hip_runtime.h>
#include <stdint.h>

// ---------------------------------------------------------------------------
// EmbraceNet fused: out[b,e] = relu(x_f @ W_f + b_f)[b,e],  f = idx[b,e]
// idx = categorical(key=42): partitionable threefry, bits = y0^y1 of
// threefry2x32((0,42), (0, (e*4096+b)*4+f)); argmax over bits>>9, strict >.
// PASS since R4 (absmax 0.031).
//
// R23: FINAL -- revert to R17 (session best, 252.79 us, gemm 86.5 us).
// R22 closed the last open lever: 8x(64x32) waves clamped VGPR to 68
// (FETCH 83->150 MB remat traffic), doubled A's LDS read sharing, and
// occupancy stayed 22% -- gemm 132 us. Full session scoreboard (gemm):
//   R10 baseline 92.5 | R11 cvmcnt-coarse 104 | R13 cvmcnt-BK32 110.5
//   R14 8phase+Ksplit 228 | R16 qphase-1blk 212 | R17 +XCD-swz 86.5 WIN
//   R19 BK32-2blk 104.6 | R22 8-wave 132
// Only levers that ever helped here: the R10 2-barrier/BK64/2-blk-CU
// structure + bijective XCD swizzle. Remaining gap to the 27.5us MFMA
// floor is structural (short-K per plane, selection fold pinning res+acc
// in regs); every published schedule fix was tested and regressed.
// ---------------------------------------------------------------------------

typedef short short8 __attribute__((ext_vector_type(8)));
typedef float floatx4 __attribute__((ext_vector_type(4)));

#define B_DIM 4096
#define K_DIM 1024
#define E_DIM 2048

__device__ __forceinline__ uint32_t rotl32(uint32_t x, uint32_t r) {
  return __builtin_amdgcn_alignbit(x, x, 32u - r);
}

__device__ __forceinline__ uint16_t f2bf(float x) {
  uint32_t u = __float_as_uint(x);
  u += 0x7FFFu + ((u >> 16) & 1u);
  return (uint16_t)(u >> 16);
}

// JAX threefry2x32, key = (0, 42)
__device__ __forceinline__ void threefry(uint32_t x0, uint32_t x1,
                                         uint32_t& o0, uint32_t& o1) {
  const uint32_t ks0 = 0u;
  const uint32_t ks1 = 42u;
  const uint32_t ks2 = 0x1BD11BDAu ^ 42u;
  x0 += ks0; x1 += ks1;
#define TF_R(r) { x0 += x1; x1 = rotl32(x1, r); x1 ^= x0; }
  TF_R(13) TF_R(15) TF_R(26) TF_R(6)
  x0 += ks1; x1 += ks2 + 1u;
  TF_R(17) TF_R(29) TF_R(16) TF_R(24)
  x0 += ks2; x1 += ks0 + 2u;
  TF_R(13) TF_R(15) TF_R(26) TF_R(6)
  x0 += ks0; x1 += ks1 + 3u;
  TF_R(17) TF_R(29) TF_R(16) TF_R(24)
  x0 += ks1; x1 += ks2 + 4u;
  TF_R(13) TF_R(15) TF_R(26) TF_R(6)
  x0 += ks2; x1 += ks0 + 5u;
#undef TF_R
  o0 = x0; o1 = x1;
}

// 8192 blocks x 256 threads. Every thread: issue x loads (8 floats) + W
// loads (4 floats), crunch 4 idx outputs (16 threefry) while loads fly,
// then store x bf16 (16B), idx byte, and W transposed tile via LDS.
__global__ __launch_bounds__(256) void prep_kernel(
    const float* __restrict__ x0, const float* __restrict__ x1,
    const float* __restrict__ x2, const float* __restrict__ x3,
    const float* __restrict__ W0, const float* __restrict__ W1,
    const float* __restrict__ W2, const float* __restrict__ W3,
    uint16_t* __restrict__ xb, uint16_t* __restrict__ Wt,
    uint8_t* __restrict__ idx1) {
  __shared__ float tile[32][33];
  const uint32_t g = blockIdx.x;       // 0..8191
  const int t = threadIdx.x;
  const int f = g >> 11;               // plane 0..3
  const uint32_t ip = g & 2047u;       // tile/chunk within plane

  // ---- issue x loads: plane f, 8 consecutive floats per thread ----
  const float* x = (f == 0) ? x0 : (f == 1) ? x1 : (f == 2) ? x2 : x3;
  const size_t xoff = ((size_t)ip * 256 + t) * 8;
  float4 v0 = *(const float4*)(x + xoff);
  float4 v1 = *(const float4*)(x + xoff + 4);

  // ---- issue W loads: 32x32 tile ip of plane f ----
  const float* W = (f == 0) ? W0 : (f == 1) ? W1 : (f == 2) ? W2 : W3;
  const int e0 = (int)(ip & 63) * 32, k0 = (int)(ip >> 6) * 32;
  const int tx = t & 31, ty = t >> 5;
  float wv[4];
#pragma unroll
  for (int i = 0; i < 4; ++i)
    wv[i] = W[(size_t)(k0 + ty + i * 8) * E_DIM + e0 + tx];

  // ---- threefry crunch: outputs o0..o0+3, pack 2 bits each ----
  const uint32_t o0i = (g * 256u + t) * 4u;
  uint32_t byte = 0;
#pragma unroll
  for (uint32_t q = 0; q < 4; ++q) {
    uint32_t c = (o0i + q) << 2;
    uint32_t best = 0, bi = 0;
#pragma unroll
    for (uint32_t ff = 0; ff < 4; ++ff) {
      uint32_t y0, y1;
      threefry(0u, c + ff, y0, y1);
      uint32_t m = (y0 ^ y1) >> 9;
      if (ff == 0) best = m;
      else if (m > best) { best = m; bi = ff; }
    }
    byte |= bi << (2 * q);
  }
  idx1[g * 256u + t] = (uint8_t)byte;

  // ---- x store: 8 bf16 = 16B ----
  {
    union { uint16_t h[8]; uint64_t q[2]; } p;
    p.h[0] = f2bf(v0.x); p.h[1] = f2bf(v0.y);
    p.h[2] = f2bf(v0.z); p.h[3] = f2bf(v0.w);
    p.h[4] = f2bf(v1.x); p.h[5] = f2bf(v1.y);
    p.h[6] = f2bf(v1.z); p.h[7] = f2bf(v1.w);
    uint64_t* dst = (uint64_t*)(xb + (size_t)f * B_DIM * K_DIM + xoff);
    dst[0] = p.q[0]; dst[1] = p.q[1];
  }

  // ---- W transpose via LDS ----
#pragma unroll
  for (int i = 0; i < 4; ++i) tile[ty + i * 8][tx] = wv[i];
  __syncthreads();
  {
    const int el = t >> 3, kc = (t & 7) * 4;
    union { uint16_t h[4]; uint64_t q; } p;
#pragma unroll
    for (int i = 0; i < 4; ++i) p.h[i] = f2bf(tile[kc + i][el]);
    uint16_t* dst = Wt + (size_t)f * E_DIM * K_DIM;
    *(uint64_t*)(dst + (size_t)(e0 + el) * K_DIM + k0 + kc) = p.q;
  }
}

__device__ __forceinline__ void async16(const uint16_t* g, uint16_t* lds) {
  __builtin_amdgcn_global_load_lds(
      (const __attribute__((address_space(1))) void*)g,
      (__attribute__((address_space(3))) void*)lds, 16, 0, 0);
}

// 256 threads (4 waves, 2x2 of 64x64), 128x128 tile, BK=64, f-loop inside,
// double-buffered LDS (64KB), one barrier per 64-K iter (64 total).
// LDS[row][pos] holds global k-chunk pos^(row&7) (XOR swizzle, 8x16B chunks).
__global__ __launch_bounds__(256, 2) void gemm_fused(
    const uint16_t* __restrict__ Ab, const uint16_t* __restrict__ Bbt,
    const uint32_t* __restrict__ idx2,
    const float* __restrict__ bias0, const float* __restrict__ bias1,
    const float* __restrict__ bias2, const float* __restrict__ bias3,
    float* __restrict__ out) {
  __shared__ uint16_t As[2][128 * 64];
  __shared__ uint16_t Bs[2][128 * 64];

  const int tid = threadIdx.x;
  const int w = tid >> 6;        // 0..3
  const int l = tid & 63;

  // bijective XCD-chunked swizzle. 512 blocks = 8 XCDs x 64 contiguous
  // tiles (m-major within chunk -> A panels L2-resident).
  const int flat = (int)(blockIdx.y * gridDim.x + blockIdx.x);
  const int swz = (flat & 7) * 64 + (flat >> 3);
  const int mBase = (swz >> 4) * 128;   // 32 m-tiles
  const int nBase = (swz & 15) * 128;   // 16 n-tiles

  const int wm = (w >> 1) * 64, wn = (w & 1) * 64;
  // staging: chunk c (8 rows of 64k); lane -> row sr, swizzled k-chunk
  const int sr = l >> 3;                 // 0..7 row within chunk
  const int skc = ((l & 7) ^ sr) * 8;    // global k-elem offset (swizzled)
  const int fr = l & 15, fq = l >> 4;

  const int b_hi0 = (mBase + wm) >> 4;
  uint32_t iw[4][4];
#pragma unroll
  for (int ni = 0; ni < 4; ++ni) {
    int col = nBase + wn + ni * 16 + fr;
#pragma unroll
    for (int mi = 0; mi < 4; ++mi)
      iw[ni][mi] = idx2[(size_t)col * (B_DIM / 16) + b_hi0 + mi];
  }

  floatx4 res[4][4] = {};

#pragma unroll 1
  for (int f = 0; f < 4; ++f) {
    const uint16_t* A = Ab  + (size_t)f * B_DIM * K_DIM + (size_t)mBase * K_DIM;
    const uint16_t* B = Bbt + (size_t)f * E_DIM * K_DIM + (size_t)nBase * K_DIM;
    // wave w stages chunks 4w..4w+3 of each matrix (chunk = 8 rows x 64 k)
    const uint16_t* Aw = A + (size_t)(32 * w + sr) * K_DIM + skc;
    const uint16_t* Bw = B + (size_t)(32 * w + sr) * K_DIM + skc;

    floatx4 acc[4][4] = {};

#pragma unroll
    for (int tt = 0; tt < 4; ++tt) {
      async16(Aw + (size_t)(8 * tt) * K_DIM, &As[0][(4 * w + tt) * 512]);
      async16(Bw + (size_t)(8 * tt) * K_DIM, &Bs[0][(4 * w + tt) * 512]);
    }
    __syncthreads();

    int buf = 0;
#pragma unroll 1
    for (int kt = 0; kt < 16; ++kt) {
      int kn = (kt + 1) * 64;
      if (kt + 1 < 16) {  // next 64-K tile into other buffer, before compute
#pragma unroll
        for (int tt = 0; tt < 4; ++tt) {
          async16(Aw + (size_t)(8 * tt) * K_DIM + kn, &As[buf ^ 1][(4 * w + tt) * 512]);
          async16(Bw + (size_t)(8 * tt) * K_DIM + kn, &Bs[buf ^ 1][(4 * w + tt) * 512]);
        }
      }
#pragma unroll
      for (int h = 0; h < 2; ++h) {
        short8 a[4], b[4];
        const int ch = h * 4 + fq;
#pragma unroll
        for (int mi = 0; mi < 4; ++mi) {
          int row = wm + mi * 16 + fr;
          a[mi] = *(const short8*)&As[buf][row * 64 + (ch ^ (fr & 7)) * 8];
        }
#pragma unroll
        for (int ni = 0; ni < 4; ++ni) {
          int row = wn + ni * 16 + fr;
          b[ni] = *(const short8*)&Bs[buf][row * 64 + (ch ^ (fr & 7)) * 8];
        }
#pragma unroll
        for (int mi = 0; mi < 4; ++mi)
#pragma unroll
          for (int ni = 0; ni < 4; ++ni)
            acc[mi][ni] = __builtin_amdgcn_mfma_f32_16x16x32_bf16(
                a[mi], b[ni], acc[mi][ni], 0, 0, 0);
      }
      __syncthreads();
      buf ^= 1;
    }

    const float* bias = (f == 0) ? bias0 : (f == 1) ? bias1
                      : (f == 2) ? bias2 : bias3;
#pragma unroll
    for (int ni = 0; ni < 4; ++ni) {
      float bvf = bias[nBase + wn + ni * 16 + fr];
#pragma unroll
      for (int mi = 0; mi < 4; ++mi) {
        uint32_t wd = iw[ni][mi];
#pragma unroll
        for (int r = 0; r < 4; ++r) {
          uint32_t sel = (wd >> (2 * (fq * 4 + r))) & 3u;
          if (sel == (uint32_t)f) res[mi][ni][r] = acc[mi][ni][r] + bvf;
        }
      }
    }
  }

  // dense coalesced store with relu. C/D: col=lane&15, row=(lane>>4)*4+reg
#pragma unroll
  for (int ni = 0; ni < 4; ++ni) {
    int col = nBase + wn + ni * 16 + fr;
#pragma unroll
    for (int mi = 0; mi < 4; ++mi) {
      int row0 = mBase + wm + mi * 16 + fq * 4;
#pragma unroll
      for (int r = 0; r < 4; ++r) {
        float o = res[mi][ni][r];
        __builtin_nontemporal_store(o > 0.f ? o : 0.f,
                                    &out[(size_t)(row0 + r) * E_DIM + col]);
      }
    }
  }
}

extern "C" void kernel_launch(void* const* d_in, const int* in_sizes, int n_in,
                              void* d_out, int out_size, void* d_ws, size_t ws_size,
                              hipStream_t stream) {
  const float* x[4]; const float* W[4]; const float* bs[4];
  for (int f = 0; f < 4; ++f) {
    x[f]  = (const float*)d_in[3 * f + 0];
    W[f]  = (const float*)d_in[3 * f + 1];
    bs[f] = (const float*)d_in[3 * f + 2];
  }
  char* ws = (char*)d_ws;
  uint16_t* xb  = (uint16_t*)ws;                               // 32 MB
  uint16_t* Wt  = (uint16_t*)(ws + (size_t)32 * 1024 * 1024);  // 16 MB
  uint8_t*  idx1 = (uint8_t*)(ws + (size_t)48 * 1024 * 1024);  //  2 MB
  float* out = (float*)d_out;

  prep_kernel<<<dim3(8192), dim3(256), 0, stream>>>(
      x[0], x[1], x[2], x[3], W[0], W[1], W[2], W[3], xb, Wt, idx1);
  gemm_fused<<<dim3(E_DIM / 128, B_DIM / 128), dim3(256), 0, stream>>>(
      xb, Wt, (const uint32_t*)idx1, bs[0], bs[1], bs[2], bs[3], out);
}